// Round 6
// baseline (472.023 us; speedup 1.0000x reference)
//
#include <hip/hip_runtime.h>
#include <hip/hip_cooperative_groups.h>

namespace cg = cooperative_groups;

typedef __bf16 bf16_t;
typedef __bf16 bf16x4 __attribute__((ext_vector_type(4)));
typedef __bf16 bf16x8 __attribute__((ext_vector_type(8)));
typedef float floatx4 __attribute__((ext_vector_type(4)));

#define G_GRAPHS 64
#define N_NODES 2000
#define N_EDGES 64000
#define BATCH 10000
#define TED_ 512
#define NOISE_ 128
#define PACDIM_ 6400
#define D0_ 1024
#define D1_ 512
#define MROWS 1000   // BATCH / PAC
#define S0 10         // split-K for layer 0 (640 blocks)
#define S1 8          // split-K for layer 1

#define FBLOCKS 256          // cooperative grid: 256 blocks -> 1/CU, always launchable
#define EPB4 (N_EDGES / 4)   // 16000 edges per block-slice (4 slices per graph)
#define TW0_TILES 6400       // (PACDIM/32) * (D0/32)
#define TW1_TILES 512        // (D0/32) * (D1/32)

// ---------------- async global->LDS helper (16B per lane) ----------------
__device__ __forceinline__ void glds16(const void* g, void* l) {
    __builtin_amdgcn_global_load_lds(
        (__attribute__((address_space(1))) void*)(g),
        (__attribute__((address_space(3))) void*)(l), 16, 0, 0);
}

// ================= fused front-end (cooperative, 256 blocks x 512 thr) =================
// phase0: zero scratch + pack input_ -> A + transpose W0/W1 to bf16 [N,K]
// phase1: per-graph degree histogram (4 edge-slices per graph)
// phase2: message pass
// phase3: gcn finish + gnoise[G,128] partial GEMV
// phase4: meta_emb + noise -> A noise columns
__global__ __launch_bounds__(512) void fused_front_kernel(
    const float* __restrict__ input_,
    const float* __restrict__ graphs_x, const int* __restrict__ edge_index,
    const int* __restrict__ graph_ids, const float* __restrict__ chain,
    const float* __restrict__ metadata,
    const float* __restrict__ gcn_w, const float* __restrict__ gcn_b,
    const float* __restrict__ meta_w, const float* __restrict__ meta_b,
    const float* __restrict__ gme_w, const float* __restrict__ gme_b,
    const float* __restrict__ seq_w0, const float* __restrict__ seq_w1,
    float* __restrict__ degs, float* __restrict__ outs, float* __restrict__ gnoise,
    bf16_t* __restrict__ A, bf16_t* __restrict__ W0t, bf16_t* __restrict__ W1t)
{
    cg::grid_group grid = cg::this_grid();
    __shared__ float smem[6000];   // 24 KB, aliased per phase
    const int tid = threadIdx.x, blk = blockIdx.x;
    const int gtid = blk * 512 + tid;          // [0, 131072)

    // ---------- phase 0a: zero gnoise|degs|outs (contiguous, 66048 float4) ----------
    {
        float4* z = (float4*)gnoise;
        if (gtid < 66048) z[gtid] = make_float4(0.f, 0.f, 0.f, 0.f);
    }
    // ---------- phase 0b: pack input_ fp32 -> A bf16 ----------
    for (int idx = gtid; idx < BATCH * TED_ / 4; idx += FBLOCKS * 512) {
        float4 v = ((const float4*)input_)[idx];
        int b = idx >> 7;                  // batch row (128 float4 per row)
        int c = (idx & 127) << 2;
        int r = b / 10, slot = b - r * 10;
        bf16x4 o = { (bf16_t)v.x, (bf16_t)v.y, (bf16_t)v.z, (bf16_t)v.w };
        *(bf16x4*)(A + (size_t)r * PACDIM_ + slot * 640 + c) = o;
    }
    // ---------- phase 0c: transpose-convert W0, W1 (32x32 tiles) ----------
    {
        int tx = tid & 31, ty = tid >> 5;    // ty in [0,16)
        float (*t)[33] = (float(*)[33])smem;
        for (int tile = blk; tile < TW0_TILES + TW1_TILES; tile += FBLOCKS) {
            const float* W; bf16_t* Wt; int R, C, c0, r0;
            if (tile < TW0_TILES) {
                W = seq_w0; Wt = W0t; R = PACDIM_; C = D0_;
                c0 = (tile & 31) * 32; r0 = (tile >> 5) * 32;
            } else {
                int l = tile - TW0_TILES;
                W = seq_w1; Wt = W1t; R = D0_; C = D1_;
                c0 = (l & 15) * 32; r0 = (l >> 4) * 32;
            }
            __syncthreads();
            for (int yy = ty; yy < 32; yy += 16)
                t[yy][tx] = W[(size_t)(r0 + yy) * C + c0 + tx];
            __syncthreads();
            for (int yy = ty; yy < 32; yy += 16)
                Wt[(size_t)(c0 + yy) * R + r0 + tx] = (bf16_t)t[tx][yy];
        }
    }
    grid.sync();
    // ---------- phase 1: degree histogram (g = blk/4, slice = blk%4) ----------
    {
        const int g = blk >> 2, s = blk & 3;
        float* h = smem;
        for (int n = tid; n < N_NODES; n += 512) h[n] = 0.f;
        __syncthreads();
        const int* dst = edge_index + (size_t)g * 2 * N_EDGES + N_EDGES + s * EPB4;
        for (int e = tid; e < EPB4; e += 512) atomicAdd(&h[dst[e]], 1.0f);
        __syncthreads();
        float* dg = degs + (size_t)g * N_NODES;
        for (int n = tid; n < N_NODES; n += 512) {
            float v = h[n];
            if (v != 0.f) atomicAdd(&dg[n], v);
        }
    }
    grid.sync();
    // ---------- phase 2: message pass ----------
    {
        const int g = blk >> 2, s = blk & 3;
        float* xsl = smem;
        float* dvl = smem + 2000;
        float* oh  = smem + 4000;
        const float* xg = graphs_x + (size_t)g * N_NODES;
        const float* dgg = degs + (size_t)g * N_NODES;
        for (int n = tid; n < N_NODES; n += 512) {
            xsl[n] = xg[n];
            dvl[n] = rsqrtf(dgg[n] + 1.0f);   // +1 self-loop
            oh[n] = 0.f;
        }
        __syncthreads();
        const int* src = edge_index + (size_t)g * 2 * N_EDGES + s * EPB4;
        const int* dst = src + N_EDGES;
        for (int e = tid; e < EPB4; e += 512) {
            int ss = src[e], dd = dst[e];
            atomicAdd(&oh[dd], xsl[ss] * dvl[ss] * dvl[dd]);
        }
        __syncthreads();
        float* og = outs + (size_t)g * N_NODES;
        for (int n = tid; n < N_NODES; n += 512) {
            float v = oh[n];
            if (v != 0.f) atomicAdd(&og[n], v);
        }
    }
    grid.sync();
    // ---------- phase 3: gcn finish + gnoise partial GEMV (500 nodes/block) ----------
    {
        const int g = blk >> 2, s = blk & 3;
        const int nBase = s * 500;
        float* of = smem;            // 500
        float* part = smem + 512;    // 4*128
        const float w = gcn_w[0], b = gcn_b[0];
        for (int n = tid; n < 500; n += 512) {
            int gn = nBase + n;
            float di2 = 1.0f / (degs[(size_t)g * N_NODES + gn] + 1.0f);
            of[n] = w * (outs[(size_t)g * N_NODES + gn]
                         + graphs_x[(size_t)g * N_NODES + gn] * di2) + b;
        }
        __syncthreads();
        const int j = tid & 127, ch = tid >> 7;
        float acc = 0.f;
        for (int n = ch; n < 500; n += 4)
            acc += of[n] * gme_w[(size_t)(nBase + n) * 128 + j];
        part[ch * 128 + j] = acc;
        __syncthreads();
        if (tid < 128)
            atomicAdd(&gnoise[(size_t)g * 128 + tid],
                      part[tid] + part[128 + tid] + part[256 + tid] + part[384 + tid]);
    }
    grid.sync();
    // ---------- phase 4: meta_emb + noise -> A noise columns (1 wave / batch row) ----------
    {
        const int lane = tid & 63;
        for (int wid = blk * 8 + (tid >> 6); wid < BATCH; wid += FBLOCKS * 8) {
            const int b = wid;
            float me = 0.f;
            if (lane < 32) {
                me = meta_b[lane] + chain[b] * meta_w[lane];
                for (int i = 1; i < 16; i++)
                    me += metadata[(size_t)b * 15 + (i - 1)] * meta_w[(size_t)i * 32 + lane];
                me = me > 0.f ? me : 0.f;
            }
            const int gid = graph_ids[b];
            const int j1 = lane, j2 = lane + 64;
            float n1 = gnoise[(size_t)gid * 128 + j1] + gme_b[j1];
            float n2 = gnoise[(size_t)gid * 128 + j2] + gme_b[j2];
            for (int k = 0; k < 32; k++) {
                float mk = __shfl(me, k, 64);
                const float* wrow = gme_w + (size_t)(N_NODES + k) * 128;
                n1 += mk * wrow[j1];
                n2 += mk * wrow[j2];
            }
            int r = b / 10, slot = b - r * 10;
            bf16_t* dp = A + (size_t)r * PACDIM_ + slot * 640 + TED_;
            dp[j1] = (bf16_t)n1;
            dp[j2] = (bf16_t)n2;
        }
    }
}

// ======== GEMM: BK=32 m97 layout (known-good), split-K ========
__global__ __launch_bounds__(256) void gemm_bt_splitk_kernel(
    const bf16_t* __restrict__ A, const bf16_t* __restrict__ Bt,
    float* __restrict__ P, int M, int N, int K, int KS)
{
    __shared__ __align__(16) bf16_t As[128 * 32];
    __shared__ __align__(16) bf16_t Bs[128 * 32];
    const int tid = threadIdx.x;
    const int wave = tid >> 6;
    const int lane = tid & 63;
    const int mBase = blockIdx.y * 128;
    const int nBase = blockIdx.x * 128;
    const int z = blockIdx.z;
    const int Mp = gridDim.y * 128;
    const int wm = (wave & 1) * 64;
    const int wn = (wave >> 1) * 64;

    floatx4 acc[4][4] = {};

    const int c0 = tid, c1 = tid + 256;
    const int rA0 = c0 >> 2, k80 = (c0 & 3) * 8;
    const int rA1 = c1 >> 2, k81 = (c1 & 3) * 8;
    int gm0 = mBase + rA0; if (gm0 > M - 1) gm0 = M - 1;
    int gm1 = mBase + rA1; if (gm1 > M - 1) gm1 = M - 1;
    const bf16_t* aP0 = A + (size_t)gm0 * K + k80;
    const bf16_t* aP1 = A + (size_t)gm1 * K + k81;
    const bf16_t* bP0 = Bt + (size_t)(nBase + rA0) * K + k80;
    const bf16_t* bP1 = Bt + (size_t)(nBase + rA1) * K + k81;
    char* lA0 = (char*)As + wave * 1024;
    char* lA1 = (char*)As + 4096 + wave * 1024;
    char* lB0 = (char*)Bs + wave * 1024;
    char* lB1 = (char*)Bs + 4096 + wave * 1024;

    const int kq = (lane >> 4) * 8;
    const int mr = lane & 15;
    const bf16x8* ra[4]; const bf16x8* rb[4];
    for (int i = 0; i < 4; i++)
        ra[i] = (const bf16x8*)&As[(wm + i * 16 + mr) * 32 + kq];
    for (int j = 0; j < 4; j++)
        rb[j] = (const bf16x8*)&Bs[(wn + j * 16 + mr) * 32 + kq];

    const int kEnd = z * KS + KS;
    for (int k0 = z * KS; k0 < kEnd; k0 += 32) {
        __syncthreads();
        glds16(aP0 + k0, lA0);
        glds16(aP1 + k0, lA1);
        glds16(bP0 + k0, lB0);
        glds16(bP1 + k0, lB1);
        __syncthreads();
        bf16x8 af[4], bfr[4];
        for (int i = 0; i < 4; i++) af[i] = *ra[i];
        for (int j = 0; j < 4; j++) bfr[j] = *rb[j];
        for (int i = 0; i < 4; i++)
            for (int j = 0; j < 4; j++)
                acc[i][j] = __builtin_amdgcn_mfma_f32_16x16x32_bf16(
                    af[i], bfr[j], acc[i][j], 0, 0, 0);
    }

    float* Pz = P + (size_t)z * Mp * N;
    const int rq = (lane >> 4) * 4;
    const int cn = lane & 15;
    for (int j = 0; j < 4; j++) {
        int col = nBase + wn + j * 16 + cn;
        for (int i = 0; i < 4; i++)
            for (int r = 0; r < 4; r++) {
                int rowm = mBase + wm + i * 16 + rq + r;
                Pz[(size_t)rowm * N + col] = acc[i][j][r];
            }
    }
}

// -------- reduce split-K partials + bias + leaky -> bf16 --------
__global__ __launch_bounds__(256) void reduce_bias_leaky_kernel(
    const float* __restrict__ P, const float* __restrict__ bias,
    bf16_t* __restrict__ C, int M, int N, int Mp, int S)
{
    int idx = blockIdx.x * 256 + threadIdx.x;
    int total = M * (N >> 2);
    if (idx >= total) return;
    int nv = N >> 2;
    int r = idx / nv, c4 = (idx - r * nv) << 2;
    size_t off = (size_t)r * N + c4;
    size_t stride = (size_t)Mp * N;
    float4 v = *(const float4*)(P + off);
    for (int s = 1; s < S; s++) {
        float4 u = *(const float4*)(P + s * stride + off);
        v.x += u.x; v.y += u.y; v.z += u.z; v.w += u.w;
    }
    const float4 bv = *(const float4*)(bias + c4);
    v.x += bv.x; v.y += bv.y; v.z += bv.z; v.w += bv.w;
    v.x = v.x > 0.f ? v.x : 0.2f * v.x;
    v.y = v.y > 0.f ? v.y : 0.2f * v.y;
    v.z = v.z > 0.f ? v.z : 0.2f * v.z;
    v.w = v.w > 0.f ? v.w : 0.2f * v.w;
    bf16x4 o = { (bf16_t)v.x, (bf16_t)v.y, (bf16_t)v.z, (bf16_t)v.w };
    *(bf16x4*)(C + off) = o;
}

// ---- fused reduce(P1) + bias + leaky + dot(w2) + b2 -> out[r] ----
__global__ __launch_bounds__(256) void final_fused_kernel(
    const float* __restrict__ P, const float* __restrict__ b1,
    const float* __restrict__ w2, const float* __restrict__ b2,
    float* __restrict__ out, int Mp, int S)
{
    int wid = (blockIdx.x * 256 + threadIdx.x) >> 6;
    int lane = threadIdx.x & 63;
    if (wid >= MROWS) return;
    size_t stride = (size_t)Mp * D1_;
    const float* base = P + (size_t)wid * D1_;
    float s = 0.f;
    for (int i = 0; i < 8; i++) {
        int c = i * 64 + lane;
        float v = base[c];
        for (int z = 1; z < S; z++) v += base[(size_t)z * stride + c];
        v += b1[c];
        v = v > 0.f ? v : 0.2f * v;
        s += v * w2[c];
    }
    for (int off = 32; off; off >>= 1) s += __shfl_down(s, off, 64);
    if (lane == 0) out[wid] = s + b2[0];
}

// ---------------------------- launcher ----------------------------
extern "C" void kernel_launch(void* const* d_in, const int* in_sizes, int n_in,
                              void* d_out, int out_size, void* d_ws, size_t ws_size,
                              hipStream_t stream)
{
    const float* input_    = (const float*)d_in[0];
    const float* graphs_x  = (const float*)d_in[1];
    const int*   edge_idx  = (const int*)  d_in[2];
    const int*   graph_ids = (const int*)  d_in[3];
    const float* chain     = (const float*)d_in[4];
    const float* metadata  = (const float*)d_in[5];
    const float* gcn_w     = (const float*)d_in[6];
    const float* gcn_b     = (const float*)d_in[7];
    const float* meta_w    = (const float*)d_in[8];
    const float* meta_b    = (const float*)d_in[9];
    const float* gme_w     = (const float*)d_in[10];
    const float* gme_b     = (const float*)d_in[11];
    const float* seq_w0    = (const float*)d_in[12];
    const float* seq_b0    = (const float*)d_in[13];
    const float* seq_w1    = (const float*)d_in[14];
    const float* seq_b1    = (const float*)d_in[15];
    const float* seq_w2    = (const float*)d_in[16];
    const float* seq_b2    = (const float*)d_in[17];
    float* out = (float*)d_out;

    char* ws = (char*)d_ws;
    // workspace layout (gnoise|degs|outs contiguous for one-shot zeroing)
    float*  gnoise = (float*)(ws + 0);              //  64*128*4    =    32768
    float*  degs   = (float*)(ws + 32768);          //  64*2000*4   =   512000
    float*  outs   = (float*)(ws + 544768);         //  64*2000*4   =   512000
    bf16_t* Abuf   = (bf16_t*)(ws + 1056768);       // 1000*6400*2  = 12800000
    bf16_t* W0t    = (bf16_t*)(ws + 13856768);      // 1024*6400*2  = 13107200
    bf16_t* W1t    = (bf16_t*)(ws + 26963968);      //  512*1024*2  =  1048576
    bf16_t* H1     = (bf16_t*)(ws + 28012544);      // 1000*1024*2  =  2048000
    float*  P      = (float*)(ws + 30060544);       // S0*1024*1024*4 = 41.9 MB
    // total ~72 MB

    // fused front-end: cooperative, 256 blocks (1/CU — always launchable)
    void* kargs[] = {
        (void*)&input_, (void*)&graphs_x, (void*)&edge_idx, (void*)&graph_ids,
        (void*)&chain, (void*)&metadata, (void*)&gcn_w, (void*)&gcn_b,
        (void*)&meta_w, (void*)&meta_b, (void*)&gme_w, (void*)&gme_b,
        (void*)&seq_w0, (void*)&seq_w1,
        (void*)&degs, (void*)&outs, (void*)&gnoise,
        (void*)&Abuf, (void*)&W0t, (void*)&W1t
    };
    hipLaunchCooperativeKernel((const void*)fused_front_kernel,
                               dim3(FBLOCKS), dim3(512), kargs, 0, stream);

    // layer 0: M=1000 N=1024 K=6400, split-K=10 (KS=640) -> 640 blocks
    gemm_bt_splitk_kernel<<<dim3(D0_ / 128, 8, S0), 256, 0, stream>>>(
        Abuf, W0t, P, MROWS, D0_, PACDIM_, PACDIM_ / S0);
    reduce_bias_leaky_kernel<<<(MROWS * D0_ / 4 + 255) / 256, 256, 0, stream>>>(
        P, seq_b0, H1, MROWS, D0_, 1024, S0);

    // layer 1: M=1000 N=512 K=1024, split-K=8 (KS=128) -> 256 blocks
    gemm_bt_splitk_kernel<<<dim3(D1_ / 128, 8, S1), 256, 0, stream>>>(
        H1, W1t, P, MROWS, D1_, D0_, D0_ / S1);
    // fused: reduce P1 + bias + leaky + dot w2 + b2 -> out
    final_fused_kernel<<<(MROWS * 64 + 255) / 256, 256, 0, stream>>>(
        P, seq_b1, seq_w2, seq_b2, out, 1024, S1);
}

// Round 7
// 359.835 us; speedup vs baseline: 1.3118x; 1.3118x over previous
//
#include <hip/hip_runtime.h>

typedef __bf16 bf16_t;
typedef __bf16 bf16x4 __attribute__((ext_vector_type(4)));
typedef __bf16 bf16x8 __attribute__((ext_vector_type(8)));
typedef float floatx4 __attribute__((ext_vector_type(4)));

#define G_GRAPHS 64
#define N_NODES 2000
#define N_EDGES 64000
#define BATCH 10000
#define TED_ 512
#define NOISE_ 128
#define PACDIM_ 6400
#define D0_ 1024
#define D1_ 512
#define MROWS 1000    // BATCH / PAC
#define ESL 16        // edge slices per graph
#define EPB16 (N_EDGES / ESL)   // 4000 edges per block
#define S0 10         // split-K layer 0 (8x8x10 = 640 blocks)
#define S1 8          // split-K layer 1
#define TW0_TILES 6400
#define TW1_TILES 512

// ---------------- async global->LDS helper (16B per lane) ----------------
__device__ __forceinline__ void glds16(const void* g, void* l) {
    __builtin_amdgcn_global_load_lds(
        (__attribute__((address_space(1))) void*)(g),
        (__attribute__((address_space(3))) void*)(l), 16, 0, 0);
}

// ------------- kernel 0: zero degs+outs (contiguous 1 MB) -------------
__global__ __launch_bounds__(256) void zero_kernel(float4* __restrict__ p, int n4) {
    int i = blockIdx.x * 256 + threadIdx.x;
    if (i < n4) p[i] = make_float4(0.f, 0.f, 0.f, 0.f);
}

// ---- kernel 1: degree histogram (16 slices/graph) + pack input_ -> A bf16 ----
__global__ __launch_bounds__(512) void deg_pack_kernel(
    const int* __restrict__ edge_index, float* __restrict__ degs,
    const float* __restrict__ input_, bf16_t* __restrict__ A)
{
    __shared__ float h[N_NODES];
    const int s = blockIdx.x, g = blockIdx.y, tid = threadIdx.x;
    for (int n = tid; n < N_NODES; n += 512) h[n] = 0.f;
    __syncthreads();
    const int* dst = edge_index + (size_t)g * 2 * N_EDGES + N_EDGES + s * EPB16;
    for (int e = tid; e < EPB16; e += 512) atomicAdd(&h[dst[e]], 1.0f);
    __syncthreads();
    float* dg = degs + (size_t)g * N_NODES;
    for (int n = tid; n < N_NODES; n += 512) {
        float v = h[n];
        if (v != 0.f) atomicAdd(&dg[n], v);
    }
    // ---- independent: pack input_ fp32 -> A bf16 (1024 blocks share) ----
    const int flat = g * ESL + s;                       // [0,1024)
    for (int idx = flat * 512 + tid; idx < BATCH * TED_ / 4; idx += 1024 * 512) {
        float4 v = ((const float4*)input_)[idx];
        int b = idx >> 7;
        int c = (idx & 127) << 2;
        int r = b / 10, slot = b - r * 10;
        bf16x4 o = { (bf16_t)v.x, (bf16_t)v.y, (bf16_t)v.z, (bf16_t)v.w };
        *(bf16x4*)(A + (size_t)r * PACDIM_ + slot * 640 + c) = o;
    }
}

// ---- kernel 2: message pass (16 slices/graph) + transpose W0 -> bf16 [N,K] ----
__global__ __launch_bounds__(512) void msg_tw0_kernel(
    const float* __restrict__ graphs_x, const int* __restrict__ edge_index,
    const float* __restrict__ degs, float* __restrict__ outs,
    const float* __restrict__ seq_w0, bf16_t* __restrict__ W0t)
{
    __shared__ float smem[6000];
    const int s = blockIdx.x, g = blockIdx.y, tid = threadIdx.x;
    float* xsl = smem;
    float* dvl = smem + 2000;
    float* oh  = smem + 4000;
    const float* xg = graphs_x + (size_t)g * N_NODES;
    const float* dgg = degs + (size_t)g * N_NODES;
    for (int n = tid; n < N_NODES; n += 512) {
        xsl[n] = xg[n];
        dvl[n] = rsqrtf(dgg[n] + 1.0f);   // +1 self-loop
        oh[n] = 0.f;
    }
    __syncthreads();
    const int* src = edge_index + (size_t)g * 2 * N_EDGES + s * EPB16;
    const int* dst = src + N_EDGES;
    for (int e = tid; e < EPB16; e += 512) {
        int ss = src[e], dd = dst[e];
        atomicAdd(&oh[dd], xsl[ss] * dvl[ss] * dvl[dd]);
    }
    __syncthreads();
    float* og = outs + (size_t)g * N_NODES;
    for (int n = tid; n < N_NODES; n += 512) {
        float v = oh[n];
        if (v != 0.f) atomicAdd(&og[n], v);
    }
    // ---- independent: transpose-convert W0 [6400,1024] -> W0t [1024,6400] ----
    float (*t)[33] = (float(*)[33])smem;
    const int flat = g * ESL + s;                       // [0,1024)
    const int tx = tid & 31, ty = tid >> 5;             // ty in [0,16)
    for (int tile = flat; tile < TW0_TILES; tile += 1024) {
        int c0 = (tile & 31) * 32, r0 = (tile >> 5) * 32;
        __syncthreads();
        for (int yy = ty; yy < 32; yy += 16)
            t[yy][tx] = seq_w0[(size_t)(r0 + yy) * D0_ + c0 + tx];
        __syncthreads();
        for (int yy = ty; yy < 32; yy += 16)
            W0t[(size_t)(c0 + yy) * PACDIM_ + r0 + tx] = (bf16_t)t[tx][yy];
    }
}

// ---- kernel 3: gcn finish + gnoise partial GEMV (no atomics) + transpose W1 ----
__global__ __launch_bounds__(512) void gnoise_tw1_kernel(
    const float* __restrict__ graphs_x, const float* __restrict__ degs,
    const float* __restrict__ outs,
    const float* __restrict__ gcn_w, const float* __restrict__ gcn_b,
    const float* __restrict__ gme_w, float* __restrict__ gnoisep,
    const float* __restrict__ seq_w1, bf16_t* __restrict__ W1t)
{
    __shared__ float sm[1600];
    const int s = blockIdx.x, g = blockIdx.y, tid = threadIdx.x;  // s in [0,4)
    float* of = sm;              // 500
    float* part = sm + 512;      // 4*128
    const int nBase = s * 500;
    const float w = gcn_w[0], b = gcn_b[0];
    for (int n = tid; n < 500; n += 512) {
        int gn = nBase + n;
        float di2 = 1.0f / (degs[(size_t)g * N_NODES + gn] + 1.0f);
        of[n] = w * (outs[(size_t)g * N_NODES + gn]
                     + graphs_x[(size_t)g * N_NODES + gn] * di2) + b;
    }
    __syncthreads();
    const int j = tid & 127, ch = tid >> 7;
    float acc = 0.f;
    for (int n = ch; n < 500; n += 4)
        acc += of[n] * gme_w[(size_t)(nBase + n) * 128 + j];
    part[ch * 128 + j] = acc;
    __syncthreads();
    if (tid < 128)
        gnoisep[(size_t)(s * G_GRAPHS + g) * 128 + tid] =
            part[tid] + part[128 + tid] + part[256 + tid] + part[384 + tid];
    // ---- independent: transpose-convert W1 [1024,512] -> W1t [512,1024] ----
    float (*t)[33] = (float(*)[33])sm;
    const int flat = g * 4 + s;                         // [0,256)
    const int tx = tid & 31, ty = tid >> 5;
    for (int tile = flat; tile < TW1_TILES; tile += 256) {
        int c0 = (tile & 15) * 32, r0 = (tile >> 4) * 32;
        __syncthreads();
        for (int yy = ty; yy < 32; yy += 16)
            t[yy][tx] = seq_w1[(size_t)(r0 + yy) * D1_ + c0 + tx];
        __syncthreads();
        for (int yy = ty; yy < 32; yy += 16)
            W1t[(size_t)(c0 + yy) * D0_ + r0 + tx] = (bf16_t)t[tx][yy];
    }
}

// ---- kernel 4: meta_emb + noise -> A noise columns (1 wave per batch row) ----
__global__ __launch_bounds__(256) void meta_kernel(
    const float* __restrict__ chain, const float* __restrict__ metadata,
    const int* __restrict__ graph_ids,
    const float* __restrict__ meta_w, const float* __restrict__ meta_b,
    const float* __restrict__ gme_w, const float* __restrict__ gme_b,
    const float* __restrict__ gnoisep, bf16_t* __restrict__ A)
{
    int wid = (blockIdx.x * 256 + threadIdx.x) >> 6;
    int lane = threadIdx.x & 63;
    if (wid >= BATCH) return;
    const int b = wid;
    float me = 0.f;
    if (lane < 32) {
        me = meta_b[lane] + chain[b] * meta_w[lane];
        for (int i = 1; i < 16; i++)
            me += metadata[(size_t)b * 15 + (i - 1)] * meta_w[(size_t)i * 32 + lane];
        me = me > 0.f ? me : 0.f;
    }
    const int gid = graph_ids[b];
    const int j1 = lane, j2 = lane + 64;
    float n1 = gme_b[j1], n2 = gme_b[j2];
    for (int s = 0; s < 4; s++) {
        const float* gp = gnoisep + (size_t)(s * G_GRAPHS + gid) * 128;
        n1 += gp[j1];
        n2 += gp[j2];
    }
    for (int k = 0; k < 32; k++) {
        float mk = __shfl(me, k, 64);
        const float* wrow = gme_w + (size_t)(N_NODES + k) * 128;
        n1 += mk * wrow[j1];
        n2 += mk * wrow[j2];
    }
    int r = b / 10, slot = b - r * 10;
    bf16_t* dp = A + (size_t)r * PACDIM_ + slot * 640 + TED_;
    dp[j1] = (bf16_t)n1;
    dp[j2] = (bf16_t)n2;
}

// ==== kernel 5: split-K GEMM, swizzled coalesced P store (layer 0) ====
// P layout: float4 index ((z*TPZ + tile)*256 + tid)*16 + (i*4+j), tile = by*gx+bx
__global__ __launch_bounds__(256) void gemm_bt_splitk_swz_kernel(
    const bf16_t* __restrict__ A, const bf16_t* __restrict__ Bt,
    float4* __restrict__ P4, int M, int N, int K, int KS)
{
    __shared__ __align__(16) bf16_t As[128 * 32];
    __shared__ __align__(16) bf16_t Bs[128 * 32];
    const int tid = threadIdx.x;
    const int wave = tid >> 6;
    const int lane = tid & 63;
    const int mBase = blockIdx.y * 128;
    const int nBase = blockIdx.x * 128;
    const int z = blockIdx.z;
    const int TPZ = gridDim.x * gridDim.y;
    const int tile = blockIdx.y * gridDim.x + blockIdx.x;
    const int wm = (wave & 1) * 64;
    const int wn = (wave >> 1) * 64;

    floatx4 acc[4][4] = {};

    const int c0 = tid, c1 = tid + 256;
    const int rA0 = c0 >> 2, k80 = (c0 & 3) * 8;
    const int rA1 = c1 >> 2, k81 = (c1 & 3) * 8;
    int gm0 = mBase + rA0; if (gm0 > M - 1) gm0 = M - 1;
    int gm1 = mBase + rA1; if (gm1 > M - 1) gm1 = M - 1;
    const bf16_t* aP0 = A + (size_t)gm0 * K + k80;
    const bf16_t* aP1 = A + (size_t)gm1 * K + k81;
    const bf16_t* bP0 = Bt + (size_t)(nBase + rA0) * K + k80;
    const bf16_t* bP1 = Bt + (size_t)(nBase + rA1) * K + k81;
    char* lA0 = (char*)As + wave * 1024;
    char* lA1 = (char*)As + 4096 + wave * 1024;
    char* lB0 = (char*)Bs + wave * 1024;
    char* lB1 = (char*)Bs + 4096 + wave * 1024;

    const int kq = (lane >> 4) * 8;
    const int mr = lane & 15;
    const bf16x8* ra[4]; const bf16x8* rb[4];
    for (int i = 0; i < 4; i++)
        ra[i] = (const bf16x8*)&As[(wm + i * 16 + mr) * 32 + kq];
    for (int j = 0; j < 4; j++)
        rb[j] = (const bf16x8*)&Bs[(wn + j * 16 + mr) * 32 + kq];

    const int kEnd = z * KS + KS;
    for (int k0 = z * KS; k0 < kEnd; k0 += 32) {
        __syncthreads();
        glds16(aP0 + k0, lA0);
        glds16(aP1 + k0, lA1);
        glds16(bP0 + k0, lB0);
        glds16(bP1 + k0, lB1);
        __syncthreads();
        bf16x8 af[4], bfr[4];
        for (int i = 0; i < 4; i++) af[i] = *ra[i];
        for (int j = 0; j < 4; j++) bfr[j] = *rb[j];
        for (int i = 0; i < 4; i++)
            for (int j = 0; j < 4; j++)
                acc[i][j] = __builtin_amdgcn_mfma_f32_16x16x32_bf16(
                    af[i], bfr[j], acc[i][j], 0, 0, 0);
    }

    // fully-coalesced thread-major partial store (16 x dwordx4)
    size_t base = ((size_t)(z * TPZ + tile) * 256 + tid) * 16;
    #pragma unroll
    for (int v = 0; v < 16; v++)
        P4[base + v] = *(float4*)&acc[v >> 2][v & 3];
}

// ---- kernel 5b: reduce swizzled partials + bias + leaky -> H1 bf16 ----
// one block per 128x128 tile; thread mapping mirrors gemm epilogue
__global__ __launch_bounds__(256) void h1red_kernel(
    const float4* __restrict__ P4, const float* __restrict__ bias,
    bf16_t* __restrict__ H1, int TPZ, int S, int gx, int M, int N)
{
    const int tile = blockIdx.x, tid = threadIdx.x;
    const int mt = tile / gx, nt = tile - mt * gx;
    const int wave = tid >> 6, lane = tid & 63;
    const int wm = (wave & 1) * 64, wn = (wave >> 1) * 64;
    const int rq = (lane >> 4) * 4, cn = lane & 15;
    #pragma unroll
    for (int v = 0; v < 16; v++) {
        size_t off = ((size_t)tile * 256 + tid) * 16 + v;
        size_t zs = (size_t)TPZ * 256 * 16;
        float4 a = P4[off];
        for (int z = 1; z < S; z++) {
            float4 u = P4[off + (size_t)z * zs];
            a.x += u.x; a.y += u.y; a.z += u.z; a.w += u.w;
        }
        const int i = v >> 2, j = v & 3;
        const int col = nt * 128 + wn + j * 16 + cn;
        const float bv = bias[col];
        const int row0 = mt * 128 + wm + i * 16 + rq;
        float vals[4] = { a.x, a.y, a.z, a.w };
        for (int r = 0; r < 4; r++) {
            int row = row0 + r;
            if (row < M) {
                float x = vals[r] + bv;
                x = x > 0.f ? x : 0.2f * x;
                H1[(size_t)row * N + col] = (bf16_t)x;
            }
        }
    }
}

// ==== kernel 6: split-K GEMM, plain P layout (layer 1) ====
__global__ __launch_bounds__(256) void gemm_bt_splitk_kernel(
    const bf16_t* __restrict__ A, const bf16_t* __restrict__ Bt,
    float* __restrict__ P, int M, int N, int K, int KS)
{
    __shared__ __align__(16) bf16_t As[128 * 32];
    __shared__ __align__(16) bf16_t Bs[128 * 32];
    const int tid = threadIdx.x;
    const int wave = tid >> 6;
    const int lane = tid & 63;
    const int mBase = blockIdx.y * 128;
    const int nBase = blockIdx.x * 128;
    const int z = blockIdx.z;
    const int Mp = gridDim.y * 128;
    const int wm = (wave & 1) * 64;
    const int wn = (wave >> 1) * 64;

    floatx4 acc[4][4] = {};

    const int c0 = tid, c1 = tid + 256;
    const int rA0 = c0 >> 2, k80 = (c0 & 3) * 8;
    const int rA1 = c1 >> 2, k81 = (c1 & 3) * 8;
    int gm0 = mBase + rA0; if (gm0 > M - 1) gm0 = M - 1;
    int gm1 = mBase + rA1; if (gm1 > M - 1) gm1 = M - 1;
    const bf16_t* aP0 = A + (size_t)gm0 * K + k80;
    const bf16_t* aP1 = A + (size_t)gm1 * K + k81;
    const bf16_t* bP0 = Bt + (size_t)(nBase + rA0) * K + k80;
    const bf16_t* bP1 = Bt + (size_t)(nBase + rA1) * K + k81;
    char* lA0 = (char*)As + wave * 1024;
    char* lA1 = (char*)As + 4096 + wave * 1024;
    char* lB0 = (char*)Bs + wave * 1024;
    char* lB1 = (char*)Bs + 4096 + wave * 1024;

    const int kq = (lane >> 4) * 8;
    const int mr = lane & 15;
    const bf16x8* ra[4]; const bf16x8* rb[4];
    for (int i = 0; i < 4; i++)
        ra[i] = (const bf16x8*)&As[(wm + i * 16 + mr) * 32 + kq];
    for (int j = 0; j < 4; j++)
        rb[j] = (const bf16x8*)&Bs[(wn + j * 16 + mr) * 32 + kq];

    const int kEnd = z * KS + KS;
    for (int k0 = z * KS; k0 < kEnd; k0 += 32) {
        __syncthreads();
        glds16(aP0 + k0, lA0);
        glds16(aP1 + k0, lA1);
        glds16(bP0 + k0, lB0);
        glds16(bP1 + k0, lB1);
        __syncthreads();
        bf16x8 af[4], bfr[4];
        for (int i = 0; i < 4; i++) af[i] = *ra[i];
        for (int j = 0; j < 4; j++) bfr[j] = *rb[j];
        for (int i = 0; i < 4; i++)
            for (int j = 0; j < 4; j++)
                acc[i][j] = __builtin_amdgcn_mfma_f32_16x16x32_bf16(
                    af[i], bfr[j], acc[i][j], 0, 0, 0);
    }

    float* Pz = P + (size_t)z * Mp * N;
    const int rq = (lane >> 4) * 4;
    const int cn = lane & 15;
    for (int j = 0; j < 4; j++) {
        int col = nBase + wn + j * 16 + cn;
        for (int i = 0; i < 4; i++)
            for (int r = 0; r < 4; r++) {
                int rowm = mBase + wm + i * 16 + rq + r;
                Pz[(size_t)rowm * N + col] = acc[i][j][r];
            }
    }
}

// ---- kernel 7: fused reduce(P1) + bias + leaky + dot(w2) + b2 -> out[r] ----
__global__ __launch_bounds__(256) void final_fused_kernel(
    const float* __restrict__ P, const float* __restrict__ b1,
    const float* __restrict__ w2, const float* __restrict__ b2,
    float* __restrict__ out, int Mp, int S)
{
    int wid = (blockIdx.x * 256 + threadIdx.x) >> 6;
    int lane = threadIdx.x & 63;
    if (wid >= MROWS) return;
    size_t stride = (size_t)Mp * D1_;
    const float* base = P + (size_t)wid * D1_;
    float s = 0.f;
    for (int i = 0; i < 8; i++) {
        int c = i * 64 + lane;
        float v = base[c];
        for (int z = 1; z < S; z++) v += base[(size_t)z * stride + c];
        v += b1[c];
        v = v > 0.f ? v : 0.2f * v;
        s += v * w2[c];
    }
    for (int off = 32; off; off >>= 1) s += __shfl_down(s, off, 64);
    if (lane == 0) out[wid] = s + b2[0];
}

// ---------------------------- launcher ----------------------------
extern "C" void kernel_launch(void* const* d_in, const int* in_sizes, int n_in,
                              void* d_out, int out_size, void* d_ws, size_t ws_size,
                              hipStream_t stream)
{
    const float* input_    = (const float*)d_in[0];
    const float* graphs_x  = (const float*)d_in[1];
    const int*   edge_idx  = (const int*)  d_in[2];
    const int*   graph_ids = (const int*)  d_in[3];
    const float* chain     = (const float*)d_in[4];
    const float* metadata  = (const float*)d_in[5];
    const float* gcn_w     = (const float*)d_in[6];
    const float* gcn_b     = (const float*)d_in[7];
    const float* meta_w    = (const float*)d_in[8];
    const float* meta_b    = (const float*)d_in[9];
    const float* gme_w     = (const float*)d_in[10];
    const float* gme_b     = (const float*)d_in[11];
    const float* seq_w0    = (const float*)d_in[12];
    const float* seq_b0    = (const float*)d_in[13];
    const float* seq_w1    = (const float*)d_in[14];
    const float* seq_b1    = (const float*)d_in[15];
    const float* seq_w2    = (const float*)d_in[16];
    const float* seq_b2    = (const float*)d_in[17];
    float* out = (float*)d_out;

    char* ws = (char*)d_ws;
    float*  gnoisep = (float*)(ws + 0);             // 4*64*128*4  =   131072
    float*  degs    = (float*)(ws + 131072);        // 64*2000*4   =   512000
    float*  outs    = (float*)(ws + 643072);        // 64*2000*4   =   512000  (degs|outs contiguous)
    bf16_t* Abuf    = (bf16_t*)(ws + 1155072);      // 1000*6400*2 = 12800000
    bf16_t* W0t     = (bf16_t*)(ws + 13955072);     // 1024*6400*2 = 13107200
    bf16_t* W1t     = (bf16_t*)(ws + 27062272);     //  512*1024*2 =  1048576
    bf16_t* H1      = (bf16_t*)(ws + 28110848);     // 1000*1024*2 =  2048000
    float*  P       = (float*)(ws + 30158848);      // 41.9 MB (reused by both layers)
    // total ~72 MB

    // GCN chain with folded prep work
    zero_kernel<<<250, 256, 0, stream>>>((float4*)degs, (512000 + 512000) / 16);
    deg_pack_kernel<<<dim3(ESL, G_GRAPHS), 512, 0, stream>>>(
        edge_idx, degs, input_, Abuf);
    msg_tw0_kernel<<<dim3(ESL, G_GRAPHS), 512, 0, stream>>>(
        graphs_x, edge_idx, degs, outs, seq_w0, W0t);
    gnoise_tw1_kernel<<<dim3(4, G_GRAPHS), 512, 0, stream>>>(
        graphs_x, degs, outs, gcn_w, gcn_b, gme_w, gnoisep, seq_w1, W1t);
    meta_kernel<<<2500, 256, 0, stream>>>(
        chain, metadata, graph_ids, meta_w, meta_b, gme_w, gme_b, gnoisep, Abuf);

    // layer 0: M=1000 N=1024 K=6400, split-K=10, swizzled coalesced partials
    gemm_bt_splitk_swz_kernel<<<dim3(D0_ / 128, 8, S0), 256, 0, stream>>>(
        Abuf, W0t, (float4*)P, MROWS, D0_, PACDIM_, PACDIM_ / S0);
    h1red_kernel<<<64, 256, 0, stream>>>(
        (const float4*)P, seq_b0, H1, 64, S0, 8, MROWS, D0_);

    // layer 1: M=1000 N=512 K=1024, split-K=8, plain partials
    gemm_bt_splitk_kernel<<<dim3(D1_ / 128, 8, S1), 256, 0, stream>>>(
        H1, W1t, P, MROWS, D1_, D0_, D0_ / S1);
    final_fused_kernel<<<(MROWS * 64 + 255) / 256, 256, 0, stream>>>(
        P, seq_b1, seq_w2, seq_b2, out, 1024, S1);
}

// Round 8
// 327.100 us; speedup vs baseline: 1.4431x; 1.1001x over previous
//
#include <hip/hip_runtime.h>

typedef __bf16 bf16_t;
typedef __bf16 bf16x4 __attribute__((ext_vector_type(4)));
typedef __bf16 bf16x8 __attribute__((ext_vector_type(8)));
typedef float floatx4 __attribute__((ext_vector_type(4)));

#define G_GRAPHS 64
#define N_NODES 2000
#define N_EDGES 64000
#define BATCH 10000
#define TED_ 512
#define NOISE_ 128
#define PACDIM_ 6400
#define D0_ 1024
#define D1_ 512
#define MROWS 1000    // BATCH / PAC
#define ESL 8         // edge slices per graph
#define EPB (N_EDGES / ESL)     // 8000 edges per block
#define NBLK (ESL * G_GRAPHS)   // 512 blocks in GCN edge kernels
#define S0 10         // split-K layer 0 (8x8x10 = 640 blocks)
#define S1 8          // split-K layer 1
#define TW0_TILES 6400
#define TW1_TILES 512

// ---------------- async global->LDS helper (16B per lane) ----------------
__device__ __forceinline__ void glds16(const void* g, void* l) {
    __builtin_amdgcn_global_load_lds(
        (__attribute__((address_space(1))) void*)(g),
        (__attribute__((address_space(3))) void*)(l), 16, 0, 0);
}

// ------------- kernel 0: zero degs+outs (contiguous 1 MB) -------------
__global__ __launch_bounds__(256) void zero_kernel(float4* __restrict__ p, int n4) {
    int i = blockIdx.x * 256 + threadIdx.x;
    if (i < n4) p[i] = make_float4(0.f, 0.f, 0.f, 0.f);
}

// ---- kernel 1: degree histogram (8 slices/graph) + pack input_ -> A bf16 ----
__global__ __launch_bounds__(512) void deg_pack_kernel(
    const int* __restrict__ edge_index, float* __restrict__ degs,
    const float* __restrict__ input_, bf16_t* __restrict__ A)
{
    __shared__ float h[N_NODES];
    const int s = blockIdx.x, g = blockIdx.y, tid = threadIdx.x;
    for (int n = tid; n < N_NODES; n += 512) h[n] = 0.f;
    __syncthreads();
    const int* dst = edge_index + (size_t)g * 2 * N_EDGES + N_EDGES + s * EPB;
    for (int e = tid; e < EPB; e += 512) atomicAdd(&h[dst[e]], 1.0f);
    __syncthreads();
    float* dg = degs + (size_t)g * N_NODES;
    for (int n = tid; n < N_NODES; n += 512) {
        float v = h[n];
        if (v != 0.f) atomicAdd(&dg[n], v);
    }
    // ---- independent: pack input_ fp32 -> A bf16 (512 blocks share) ----
    const int flat = g * ESL + s;                       // [0,512)
    for (int idx = flat * 512 + tid; idx < BATCH * TED_ / 4; idx += NBLK * 512) {
        float4 v = ((const float4*)input_)[idx];
        int b = idx >> 7;
        int c = (idx & 127) << 2;
        int r = b / 10, slot = b - r * 10;
        bf16x4 o = { (bf16_t)v.x, (bf16_t)v.y, (bf16_t)v.z, (bf16_t)v.w };
        *(bf16x4*)(A + (size_t)r * PACDIM_ + slot * 640 + c) = o;
    }
}

// ---- kernel 2: message pass (8 slices/graph) + transpose W0 -> bf16 [N,K] ----
__global__ __launch_bounds__(512) void msg_tw0_kernel(
    const float* __restrict__ graphs_x, const int* __restrict__ edge_index,
    const float* __restrict__ degs, float* __restrict__ outs,
    const float* __restrict__ seq_w0, bf16_t* __restrict__ W0t)
{
    __shared__ float smem[6000];
    const int s = blockIdx.x, g = blockIdx.y, tid = threadIdx.x;
    float* xsl = smem;
    float* dvl = smem + 2000;
    float* oh  = smem + 4000;
    const float* xg = graphs_x + (size_t)g * N_NODES;
    const float* dgg = degs + (size_t)g * N_NODES;
    for (int n = tid; n < N_NODES; n += 512) {
        xsl[n] = xg[n];
        dvl[n] = rsqrtf(dgg[n] + 1.0f);   // +1 self-loop
        oh[n] = 0.f;
    }
    __syncthreads();
    const int* src = edge_index + (size_t)g * 2 * N_EDGES + s * EPB;
    const int* dst = src + N_EDGES;
    for (int e = tid; e < EPB; e += 512) {
        int ss = src[e], dd = dst[e];
        atomicAdd(&oh[dd], xsl[ss] * dvl[ss] * dvl[dd]);
    }
    __syncthreads();
    float* og = outs + (size_t)g * N_NODES;
    for (int n = tid; n < N_NODES; n += 512) {
        float v = oh[n];
        if (v != 0.f) atomicAdd(&og[n], v);
    }
    // ---- independent: transpose-convert W0 [6400,1024] -> W0t [1024,6400] ----
    float (*t)[33] = (float(*)[33])smem;
    const int flat = g * ESL + s;                       // [0,512)
    const int tx = tid & 31, ty = tid >> 5;             // ty in [0,16)
    for (int tile = flat; tile < TW0_TILES; tile += NBLK) {
        int c0 = (tile & 31) * 32, r0 = (tile >> 5) * 32;
        __syncthreads();
        for (int yy = ty; yy < 32; yy += 16)
            t[yy][tx] = seq_w0[(size_t)(r0 + yy) * D0_ + c0 + tx];
        __syncthreads();
        for (int yy = ty; yy < 32; yy += 16)
            W0t[(size_t)(c0 + yy) * PACDIM_ + r0 + tx] = (bf16_t)t[tx][yy];
    }
}

// ---- kernel 3: gcn finish + gnoise partial GEMV (no atomics) + transpose W1 ----
__global__ __launch_bounds__(512) void gnoise_tw1_kernel(
    const float* __restrict__ graphs_x, const float* __restrict__ degs,
    const float* __restrict__ outs,
    const float* __restrict__ gcn_w, const float* __restrict__ gcn_b,
    const float* __restrict__ gme_w, float* __restrict__ gnoisep,
    const float* __restrict__ seq_w1, bf16_t* __restrict__ W1t)
{
    __shared__ float sm[1600];
    const int s = blockIdx.x, g = blockIdx.y, tid = threadIdx.x;  // s in [0,4)
    float* of = sm;              // 500
    float* part = sm + 512;      // 4*128
    const int nBase = s * 500;
    const float w = gcn_w[0], b = gcn_b[0];
    for (int n = tid; n < 500; n += 512) {
        int gn = nBase + n;
        float di2 = 1.0f / (degs[(size_t)g * N_NODES + gn] + 1.0f);
        of[n] = w * (outs[(size_t)g * N_NODES + gn]
                     + graphs_x[(size_t)g * N_NODES + gn] * di2) + b;
    }
    __syncthreads();
    const int j = tid & 127, ch = tid >> 7;
    float acc = 0.f;
    for (int n = ch; n < 500; n += 4)
        acc += of[n] * gme_w[(size_t)(nBase + n) * 128 + j];
    part[ch * 128 + j] = acc;
    __syncthreads();
    if (tid < 128)
        gnoisep[(size_t)(s * G_GRAPHS + g) * 128 + tid] =
            part[tid] + part[128 + tid] + part[256 + tid] + part[384 + tid];
    // ---- independent: transpose-convert W1 [1024,512] -> W1t [512,1024] ----
    float (*t)[33] = (float(*)[33])sm;
    const int flat = g * 4 + s;                         // [0,256)
    const int tx = tid & 31, ty = tid >> 5;
    for (int tile = flat; tile < TW1_TILES; tile += 256) {
        int c0 = (tile & 15) * 32, r0 = (tile >> 4) * 32;
        __syncthreads();
        for (int yy = ty; yy < 32; yy += 16)
            t[yy][tx] = seq_w1[(size_t)(r0 + yy) * D1_ + c0 + tx];
        __syncthreads();
        for (int yy = ty; yy < 32; yy += 16)
            W1t[(size_t)(c0 + yy) * D0_ + r0 + tx] = (bf16_t)t[tx][yy];
    }
}

// ---- kernel 4: meta_emb + noise -> A noise columns (1 wave per batch row) ----
__global__ __launch_bounds__(256) void meta_kernel(
    const float* __restrict__ chain, const float* __restrict__ metadata,
    const int* __restrict__ graph_ids,
    const float* __restrict__ meta_w, const float* __restrict__ meta_b,
    const float* __restrict__ gme_w, const float* __restrict__ gme_b,
    const float* __restrict__ gnoisep, bf16_t* __restrict__ A)
{
    int wid = (blockIdx.x * 256 + threadIdx.x) >> 6;
    int lane = threadIdx.x & 63;
    if (wid >= BATCH) return;
    const int b = wid;
    float me = 0.f;
    if (lane < 32) {
        me = meta_b[lane] + chain[b] * meta_w[lane];
        for (int i = 1; i < 16; i++)
            me += metadata[(size_t)b * 15 + (i - 1)] * meta_w[(size_t)i * 32 + lane];
        me = me > 0.f ? me : 0.f;
    }
    const int gid = graph_ids[b];
    const int j1 = lane, j2 = lane + 64;
    float n1 = gme_b[j1], n2 = gme_b[j2];
    for (int s = 0; s < 4; s++) {
        const float* gp = gnoisep + (size_t)(s * G_GRAPHS + gid) * 128;
        n1 += gp[j1];
        n2 += gp[j2];
    }
    for (int k = 0; k < 32; k++) {
        float mk = __shfl(me, k, 64);
        const float* wrow = gme_w + (size_t)(N_NODES + k) * 128;
        n1 += mk * wrow[j1];
        n2 += mk * wrow[j2];
    }
    int r = b / 10, slot = b - r * 10;
    bf16_t* dp = A + (size_t)r * PACDIM_ + slot * 640 + TED_;
    dp[j1] = (bf16_t)n1;
    dp[j2] = (bf16_t)n2;
}

// ==== kernel 5: split-K GEMM, swizzled coalesced P store (layer 0) ====
// P layout: float4 index ((z*TPZ + tile)*256 + tid)*16 + (i*4+j), tile = by*gx+bx
__global__ __launch_bounds__(256) void gemm_bt_splitk_swz_kernel(
    const bf16_t* __restrict__ A, const bf16_t* __restrict__ Bt,
    float4* __restrict__ P4, int M, int N, int K, int KS)
{
    __shared__ __align__(16) bf16_t As[128 * 32];
    __shared__ __align__(16) bf16_t Bs[128 * 32];
    const int tid = threadIdx.x;
    const int wave = tid >> 6;
    const int lane = tid & 63;
    const int mBase = blockIdx.y * 128;
    const int nBase = blockIdx.x * 128;
    const int z = blockIdx.z;
    const int TPZ = gridDim.x * gridDim.y;
    const int tile = blockIdx.y * gridDim.x + blockIdx.x;
    const int wm = (wave & 1) * 64;
    const int wn = (wave >> 1) * 64;

    floatx4 acc[4][4] = {};

    const int c0 = tid, c1 = tid + 256;
    const int rA0 = c0 >> 2, k80 = (c0 & 3) * 8;
    const int rA1 = c1 >> 2, k81 = (c1 & 3) * 8;
    int gm0 = mBase + rA0; if (gm0 > M - 1) gm0 = M - 1;
    int gm1 = mBase + rA1; if (gm1 > M - 1) gm1 = M - 1;
    const bf16_t* aP0 = A + (size_t)gm0 * K + k80;
    const bf16_t* aP1 = A + (size_t)gm1 * K + k81;
    const bf16_t* bP0 = Bt + (size_t)(nBase + rA0) * K + k80;
    const bf16_t* bP1 = Bt + (size_t)(nBase + rA1) * K + k81;
    char* lA0 = (char*)As + wave * 1024;
    char* lA1 = (char*)As + 4096 + wave * 1024;
    char* lB0 = (char*)Bs + wave * 1024;
    char* lB1 = (char*)Bs + 4096 + wave * 1024;

    const int kq = (lane >> 4) * 8;
    const int mr = lane & 15;
    const bf16x8* ra[4]; const bf16x8* rb[4];
    for (int i = 0; i < 4; i++)
        ra[i] = (const bf16x8*)&As[(wm + i * 16 + mr) * 32 + kq];
    for (int j = 0; j < 4; j++)
        rb[j] = (const bf16x8*)&Bs[(wn + j * 16 + mr) * 32 + kq];

    const int kEnd = z * KS + KS;
    for (int k0 = z * KS; k0 < kEnd; k0 += 32) {
        __syncthreads();
        glds16(aP0 + k0, lA0);
        glds16(aP1 + k0, lA1);
        glds16(bP0 + k0, lB0);
        glds16(bP1 + k0, lB1);
        __syncthreads();
        bf16x8 af[4], bfr[4];
        for (int i = 0; i < 4; i++) af[i] = *ra[i];
        for (int j = 0; j < 4; j++) bfr[j] = *rb[j];
        for (int i = 0; i < 4; i++)
            for (int j = 0; j < 4; j++)
                acc[i][j] = __builtin_amdgcn_mfma_f32_16x16x32_bf16(
                    af[i], bfr[j], acc[i][j], 0, 0, 0);
    }

    // fully-coalesced thread-major partial store (16 x dwordx4)
    size_t base = ((size_t)(z * TPZ + tile) * 256 + tid) * 16;
    #pragma unroll
    for (int v = 0; v < 16; v++)
        P4[base + v] = *(float4*)&acc[v >> 2][v & 3];
}

// ---- kernel 5b: FLAT reduce of swizzled partials + bias + leaky -> H1 bf16 ----
// one thread per (tile,tid,v) float4; grid = TPZ*16 blocks of 256
__global__ __launch_bounds__(256) void h1red_kernel(
    const float4* __restrict__ P4, const float* __restrict__ bias,
    bf16_t* __restrict__ H1, int TPZ, int S, int gx, int M, int N)
{
    const int f = blockIdx.x * 256 + threadIdx.x;     // [0, TPZ*4096)
    if (f >= TPZ * 4096) return;
    const size_t zs = (size_t)TPZ * 4096;
    float4 a = P4[f];
    for (int z = 1; z < S; z++) {
        float4 u = P4[f + (size_t)z * zs];
        a.x += u.x; a.y += u.y; a.z += u.z; a.w += u.w;
    }
    const int tile = f >> 12;
    const int tid  = (f >> 4) & 255;
    const int v    = f & 15;
    const int mt = tile / gx, nt = tile - mt * gx;
    const int wave = tid >> 6, lane = tid & 63;
    const int wm = (wave & 1) * 64, wn = (wave >> 1) * 64;
    const int rq = (lane >> 4) * 4, cn = lane & 15;
    const int i = v >> 2, j = v & 3;
    const int col = nt * 128 + wn + j * 16 + cn;
    const int row0 = mt * 128 + wm + i * 16 + rq;
    const float bv = bias[col];
    float vals[4] = { a.x, a.y, a.z, a.w };
    #pragma unroll
    for (int r = 0; r < 4; r++) {
        int row = row0 + r;
        if (row < M) {
            float x = vals[r] + bv;
            x = x > 0.f ? x : 0.2f * x;
            H1[(size_t)row * N + col] = (bf16_t)x;
        }
    }
}

// ==== kernel 6: split-K GEMM, plain P layout (layer 1) ====
__global__ __launch_bounds__(256) void gemm_bt_splitk_kernel(
    const bf16_t* __restrict__ A, const bf16_t* __restrict__ Bt,
    float* __restrict__ P, int M, int N, int K, int KS)
{
    __shared__ __align__(16) bf16_t As[128 * 32];
    __shared__ __align__(16) bf16_t Bs[128 * 32];
    const int tid = threadIdx.x;
    const int wave = tid >> 6;
    const int lane = tid & 63;
    const int mBase = blockIdx.y * 128;
    const int nBase = blockIdx.x * 128;
    const int z = blockIdx.z;
    const int Mp = gridDim.y * 128;
    const int wm = (wave & 1) * 64;
    const int wn = (wave >> 1) * 64;

    floatx4 acc[4][4] = {};

    const int c0 = tid, c1 = tid + 256;
    const int rA0 = c0 >> 2, k80 = (c0 & 3) * 8;
    const int rA1 = c1 >> 2, k81 = (c1 & 3) * 8;
    int gm0 = mBase + rA0; if (gm0 > M - 1) gm0 = M - 1;
    int gm1 = mBase + rA1; if (gm1 > M - 1) gm1 = M - 1;
    const bf16_t* aP0 = A + (size_t)gm0 * K + k80;
    const bf16_t* aP1 = A + (size_t)gm1 * K + k81;
    const bf16_t* bP0 = Bt + (size_t)(nBase + rA0) * K + k80;
    const bf16_t* bP1 = Bt + (size_t)(nBase + rA1) * K + k81;
    char* lA0 = (char*)As + wave * 1024;
    char* lA1 = (char*)As + 4096 + wave * 1024;
    char* lB0 = (char*)Bs + wave * 1024;
    char* lB1 = (char*)Bs + 4096 + wave * 1024;

    const int kq = (lane >> 4) * 8;
    const int mr = lane & 15;
    const bf16x8* ra[4]; const bf16x8* rb[4];
    for (int i = 0; i < 4; i++)
        ra[i] = (const bf16x8*)&As[(wm + i * 16 + mr) * 32 + kq];
    for (int j = 0; j < 4; j++)
        rb[j] = (const bf16x8*)&Bs[(wn + j * 16 + mr) * 32 + kq];

    const int kEnd = z * KS + KS;
    for (int k0 = z * KS; k0 < kEnd; k0 += 32) {
        __syncthreads();
        glds16(aP0 + k0, lA0);
        glds16(aP1 + k0, lA1);
        glds16(bP0 + k0, lB0);
        glds16(bP1 + k0, lB1);
        __syncthreads();
        bf16x8 af[4], bfr[4];
        for (int i = 0; i < 4; i++) af[i] = *ra[i];
        for (int j = 0; j < 4; j++) bfr[j] = *rb[j];
        for (int i = 0; i < 4; i++)
            for (int j = 0; j < 4; j++)
                acc[i][j] = __builtin_amdgcn_mfma_f32_16x16x32_bf16(
                    af[i], bfr[j], acc[i][j], 0, 0, 0);
    }

    float* Pz = P + (size_t)z * Mp * N;
    const int rq = (lane >> 4) * 4;
    const int cn = lane & 15;
    for (int j = 0; j < 4; j++) {
        int col = nBase + wn + j * 16 + cn;
        for (int i = 0; i < 4; i++)
            for (int r = 0; r < 4; r++) {
                int rowm = mBase + wm + i * 16 + rq + r;
                Pz[(size_t)rowm * N + col] = acc[i][j][r];
            }
    }
}

// ---- kernel 7: fused reduce(P1) + bias + leaky + dot(w2) + b2 -> out[r] ----
__global__ __launch_bounds__(256) void final_fused_kernel(
    const float* __restrict__ P, const float* __restrict__ b1,
    const float* __restrict__ w2, const float* __restrict__ b2,
    float* __restrict__ out, int Mp, int S)
{
    int wid = (blockIdx.x * 256 + threadIdx.x) >> 6;
    int lane = threadIdx.x & 63;
    if (wid >= MROWS) return;
    size_t stride = (size_t)Mp * D1_;
    const float* base = P + (size_t)wid * D1_;
    float s = 0.f;
    for (int i = 0; i < 8; i++) {
        int c = i * 64 + lane;
        float v = base[c];
        for (int z = 1; z < S; z++) v += base[(size_t)z * stride + c];
        v += b1[c];
        v = v > 0.f ? v : 0.2f * v;
        s += v * w2[c];
    }
    for (int off = 32; off; off >>= 1) s += __shfl_down(s, off, 64);
    if (lane == 0) out[wid] = s + b2[0];
}

// ---------------------------- launcher ----------------------------
extern "C" void kernel_launch(void* const* d_in, const int* in_sizes, int n_in,
                              void* d_out, int out_size, void* d_ws, size_t ws_size,
                              hipStream_t stream)
{
    const float* input_    = (const float*)d_in[0];
    const float* graphs_x  = (const float*)d_in[1];
    const int*   edge_idx  = (const int*)  d_in[2];
    const int*   graph_ids = (const int*)  d_in[3];
    const float* chain     = (const float*)d_in[4];
    const float* metadata  = (const float*)d_in[5];
    const float* gcn_w     = (const float*)d_in[6];
    const float* gcn_b     = (const float*)d_in[7];
    const float* meta_w    = (const float*)d_in[8];
    const float* meta_b    = (const float*)d_in[9];
    const float* gme_w     = (const float*)d_in[10];
    const float* gme_b     = (const float*)d_in[11];
    const float* seq_w0    = (const float*)d_in[12];
    const float* seq_b0    = (const float*)d_in[13];
    const float* seq_w1    = (const float*)d_in[14];
    const float* seq_b1    = (const float*)d_in[15];
    const float* seq_w2    = (const float*)d_in[16];
    const float* seq_b2    = (const float*)d_in[17];
    float* out = (float*)d_out;

    char* ws = (char*)d_ws;
    float*  gnoisep = (float*)(ws + 0);             // 4*64*128*4  =   131072
    float*  degs    = (float*)(ws + 131072);        // 64*2000*4   =   512000
    float*  outs    = (float*)(ws + 643072);        // 64*2000*4   =   512000  (degs|outs contiguous)
    bf16_t* Abuf    = (bf16_t*)(ws + 1155072);      // 1000*6400*2 = 12800000
    bf16_t* W0t     = (bf16_t*)(ws + 13955072);     // 1024*6400*2 = 13107200
    bf16_t* W1t     = (bf16_t*)(ws + 27062272);     //  512*1024*2 =  1048576
    bf16_t* H1      = (bf16_t*)(ws + 28110848);     // 1000*1024*2 =  2048000
    float*  P       = (float*)(ws + 30158848);      // 41.9 MB (reused by both layers)
    // total ~72 MB

    // GCN chain with folded prep work
    zero_kernel<<<250, 256, 0, stream>>>((float4*)degs, (512000 + 512000) / 16);
    deg_pack_kernel<<<dim3(ESL, G_GRAPHS), 512, 0, stream>>>(
        edge_idx, degs, input_, Abuf);
    msg_tw0_kernel<<<dim3(ESL, G_GRAPHS), 512, 0, stream>>>(
        graphs_x, edge_idx, degs, outs, seq_w0, W0t);
    gnoise_tw1_kernel<<<dim3(4, G_GRAPHS), 512, 0, stream>>>(
        graphs_x, degs, outs, gcn_w, gcn_b, gme_w, gnoisep, seq_w1, W1t);
    meta_kernel<<<2500, 256, 0, stream>>>(
        chain, metadata, graph_ids, meta_w, meta_b, gme_w, gme_b, gnoisep, Abuf);

    // layer 0: M=1000 N=1024 K=6400, split-K=10, swizzled coalesced partials
    gemm_bt_splitk_swz_kernel<<<dim3(D0_ / 128, 8, S0), 256, 0, stream>>>(
        Abuf, W0t, (float4*)P, MROWS, D0_, PACDIM_, PACDIM_ / S0);
    h1red_kernel<<<64 * 16, 256, 0, stream>>>(
        (const float4*)P, seq_b0, H1, 64, S0, 8, MROWS, D0_);

    // layer 1: M=1000 N=512 K=1024, split-K=8, plain partials
    gemm_bt_splitk_kernel<<<dim3(D1_ / 128, 8, S1), 256, 0, stream>>>(
        H1, W1t, P, MROWS, D1_, D0_, D0_ / S1);
    final_fused_kernel<<<(MROWS * 64 + 255) / 256, 256, 0, stream>>>(
        P, seq_b1, seq_w2, seq_b2, out, 1024, S1);
}